// Round 1
// baseline (2581.480 us; speedup 1.0000x reference)
//
#include <hip/hip_runtime.h>
#include <hip/hip_bf16.h>
#include <math.h>

// Problem constants
#define BQ      16          // batch
#define CDIM    256         // model dim
#define TLEN    1024        // sequence length
#define CTXL    48          // context length
#define CHUNKL  16
#define NLAYER  4
#define NHEADS  8
#define DHEAD   32          // 256/8
#define FFDIM   1024
#define NWIN    64          // T / CHUNK
#define WINL    64          // CTX_LEN + CHUNK
#define EXTL    1072        // CTX_LEN + T

// ---------------------------------------------------------------------------
// Depthwise causal conv: tmp[b][c][t] = sum_l filt[b][c][l] * x[b][c][t-31+l]
// filt = mean over axis 1 of embedding (B,2,C,32)
// ---------------------------------------------------------------------------
__global__ void conv_kernel(const float* __restrict__ x,
                            const float* __restrict__ emb,
                            float* __restrict__ tmp) {
    int bc = blockIdx.x;             // b*256 + c
    int b = bc >> 8, c = bc & 255;
    __shared__ float xs[31 + TLEN];
    __shared__ float f[32];
    int t = threadIdx.x;
    if (t < 31) xs[t] = 0.f;
    const float* xrow = x + (size_t)bc * TLEN;
    for (int s = t; s < TLEN; s += 256) xs[31 + s] = xrow[s];
    if (t < 32) {
        const float* e0 = emb + (((size_t)b * 2 + 0) * CDIM + c) * 32;
        const float* e1 = emb + (((size_t)b * 2 + 1) * CDIM + c) * 32;
        f[t] = 0.5f * (e0[t] + e1[t]);
    }
    __syncthreads();
    float* orow = tmp + (size_t)bc * TLEN;
    for (int s = t; s < TLEN; s += 256) {
        float acc = 0.f;
#pragma unroll
        for (int l = 0; l < 32; ++l) acc += f[l] * xs[s + l];
        orow[s] = acc;
    }
}

// ---------------------------------------------------------------------------
// Batched transpose: in (B, R, S) -> out (B, S, R)
// grid: (S/32, R/32, B), block (32, 8)
// ---------------------------------------------------------------------------
__global__ void transpose_kernel(const float* __restrict__ in,
                                 float* __restrict__ out, int R, int S) {
    __shared__ float tile[32][33];
    int b = blockIdx.z;
    int s0 = blockIdx.x * 32, r0 = blockIdx.y * 32;
    const float* inb = in + (size_t)b * R * S;
    float* outb = out + (size_t)b * R * S;
    int tx = threadIdx.x, ty = threadIdx.y;
    for (int i = ty; i < 32; i += 8)
        tile[i][tx] = inb[(size_t)(r0 + i) * S + s0 + tx];
    __syncthreads();
    for (int i = ty; i < 32; i += 8)
        outb[(size_t)(s0 + i) * R + r0 + tx] = tile[tx][i];
}

// ---------------------------------------------------------------------------
// ctx_out[b][layer][r][c] = act[b][976 + r][c]
// ---------------------------------------------------------------------------
__global__ void ctx_copy_kernel(const float* __restrict__ act,
                                float* __restrict__ ctx_out, int layer) {
    int idx = blockIdx.x * 256 + threadIdx.x;    // < 16*48*256
    int c = idx & 255;
    int r = (idx >> 8) % CTXL;
    int b = idx / (CTXL * CDIM);
    ctx_out[(((size_t)b * NLAYER + layer) * CTXL + r) * CDIM + c] =
        act[((size_t)b * TLEN + (TLEN - CTXL) + r) * CDIM + c];
}

// ---------------------------------------------------------------------------
// Generic fp32 GEMM: out[m][n] = sum_k Arow(m)[k] * W[n][k] + bias[n]
//                                (+ resid[m][n]) (relu optional)
// mode 0: Arow(m) = A + m*K
// mode 1 (ext tokens for K/V): m -> (b = m/1072, e = m%1072);
//         e < 48 ? ctx[b][layer][e][:] : A (act) [b][e-48][:]   (K == 256)
// Tile 64x64x32, 256 threads, 4x4 micro-tile.
// ---------------------------------------------------------------------------
__global__ __launch_bounds__(256) void gemm_kernel(
    const float* __restrict__ A, const float* __restrict__ ctx,
    int mode, int layer,
    const float* __restrict__ W, const float* __restrict__ bias,
    const float* __restrict__ resid, float* __restrict__ out,
    int M, int N, int K, int relu) {
    __shared__ float As[64][33];
    __shared__ float Ws[64][33];
    int tid = threadIdx.x;
    int tx = tid & 15, ty = tid >> 4;
    int m0 = blockIdx.y * 64, n0 = blockIdx.x * 64;
    float acc[4][4] = {};
    for (int kt = 0; kt < K; kt += 32) {
#pragma unroll
        for (int s = 0; s < 8; ++s) {
            int li = tid + s * 256;       // 0..2047
            int m = li >> 5, k = li & 31;
            int mg = m0 + m;
            const float* arow;
            if (mode == 0) {
                arow = A + (size_t)mg * K;
            } else {
                int b = mg / EXTL;
                int e = mg - b * EXTL;
                arow = (e < CTXL)
                    ? ctx + (((size_t)b * NLAYER + layer) * CTXL + e) * CDIM
                    : A + ((size_t)b * TLEN + (e - CTXL)) * CDIM;
            }
            As[m][k] = arow[kt + k];
            Ws[m][k] = W[(size_t)(n0 + m) * K + kt + k];
        }
        __syncthreads();
#pragma unroll
        for (int k = 0; k < 32; ++k) {
            float a[4], w[4];
#pragma unroll
            for (int i = 0; i < 4; ++i) a[i] = As[ty + 16 * i][k];
#pragma unroll
            for (int j = 0; j < 4; ++j) w[j] = Ws[tx + 16 * j][k];
#pragma unroll
            for (int i = 0; i < 4; ++i)
#pragma unroll
                for (int j = 0; j < 4; ++j) acc[i][j] += a[i] * w[j];
        }
        __syncthreads();
    }
#pragma unroll
    for (int i = 0; i < 4; ++i) {
        int m = m0 + ty + 16 * i;
#pragma unroll
        for (int j = 0; j < 4; ++j) {
            int n = n0 + tx + 16 * j;
            float v = acc[i][j] + bias[n];
            if (resid) v += resid[(size_t)m * N + n];
            if (relu) v = fmaxf(v, 0.f);
            out[(size_t)m * N + n] = v;
        }
    }
}

// ---------------------------------------------------------------------------
// Windowed attention, one wave per (head, window, batch).
// Q: (B, T, C); K,V: (B, 1072, C); O: (B, T, C)
// ---------------------------------------------------------------------------
__global__ void attn_kernel(const float* __restrict__ Q,
                            const float* __restrict__ K,
                            const float* __restrict__ V,
                            float* __restrict__ O) {
    int h = blockIdx.x, n = blockIdx.y, b = blockIdx.z;
    __shared__ float qs[16][33];
    __shared__ float ks[64][33];
    __shared__ float vs[64][33];
    __shared__ float ss[16][65];
    int t = threadIdx.x;   // 0..63
    const float* Qb = Q + ((size_t)b * TLEN + n * CHUNKL) * CDIM + h * DHEAD;
    const float* Kb = K + ((size_t)b * EXTL + n * CHUNKL) * CDIM + h * DHEAD;
    const float* Vb = V + ((size_t)b * EXTL + n * CHUNKL) * CDIM + h * DHEAD;
#pragma unroll
    for (int s = 0; s < 8; ++s) {
        int idx = t + s * 64;
        int r = idx >> 5, d = idx & 31;
        qs[r][d] = Qb[(size_t)r * CDIM + d];
    }
#pragma unroll
    for (int s = 0; s < 32; ++s) {
        int idx = t + s * 64;
        int r = idx >> 5, d = idx & 31;
        ks[r][d] = Kb[(size_t)r * CDIM + d];
        vs[r][d] = Vb[(size_t)r * CDIM + d];
    }
    __syncthreads();
    const float scale = 0.17677669529663687f;  // 1/sqrt(32)
    int w = t;
    for (int r = 0; r < 16; ++r) {
        float acc = 0.f;
#pragma unroll
        for (int d = 0; d < 32; ++d) acc += qs[r][d] * ks[w][d];
        ss[r][w] = acc * scale;
    }
    __syncthreads();
    if (t < 16) {
        float m = -1e30f;
        for (int w2 = 0; w2 < 64; ++w2) m = fmaxf(m, ss[t][w2]);
        float sum = 0.f;
        for (int w2 = 0; w2 < 64; ++w2) {
            float e = expf(ss[t][w2] - m);
            ss[t][w2] = e;
            sum += e;
        }
        float inv = 1.f / sum;
        for (int w2 = 0; w2 < 64; ++w2) ss[t][w2] *= inv;
    }
    __syncthreads();
    int d = t & 31, r0 = t >> 5;
    float* Ob = O + ((size_t)b * TLEN + n * CHUNKL) * CDIM + h * DHEAD;
    for (int r = r0; r < 16; r += 2) {
        float acc = 0.f;
#pragma unroll
        for (int w2 = 0; w2 < 64; ++w2) acc += ss[r][w2] * vs[w2][d];
        Ob[(size_t)r * CDIM + d] = acc;
    }
}

// ---------------------------------------------------------------------------
// LayerNorm over C=256, one wave (64 lanes) per token, 4 tokens per block.
// ---------------------------------------------------------------------------
__global__ void ln_kernel(const float* __restrict__ pre,
                          const float* __restrict__ g,
                          const float* __restrict__ beta,
                          float* __restrict__ out) {
    int tok = blockIdx.x * 4 + (threadIdx.x >> 6);
    int lane = threadIdx.x & 63;
    const float* p = pre + (size_t)tok * CDIM;
    float v[4];
    float s1 = 0.f, s2 = 0.f;
#pragma unroll
    for (int j = 0; j < 4; ++j) {
        float x = p[lane + 64 * j];
        v[j] = x;
        s1 += x;
        s2 += x * x;
    }
#pragma unroll
    for (int off = 32; off >= 1; off >>= 1) {
        s1 += __shfl_xor(s1, off, 64);
        s2 += __shfl_xor(s2, off, 64);
    }
    float mu = s1 * (1.f / 256.f);
    float var = s2 * (1.f / 256.f) - mu * mu;
    float inv = rsqrtf(var + 1e-5f);
    float* o = out + (size_t)tok * CDIM;
#pragma unroll
    for (int j = 0; j < 4; ++j) {
        int c = lane + 64 * j;
        o[c] = (v[j] - mu) * inv * g[c] + beta[c];
    }
}

// ---------------------------------------------------------------------------
extern "C" void kernel_launch(void* const* d_in, const int* in_sizes, int n_in,
                              void* d_out, int out_size, void* d_ws, size_t ws_size,
                              hipStream_t stream) {
    const float* x    = (const float*)d_in[0];
    const float* emb  = (const float*)d_in[1];
    const float* ctx  = (const float*)d_in[2];
    const float* Wqkv = (const float*)d_in[3];
    const float* bqkv = (const float*)d_in[4];
    const float* Wo   = (const float*)d_in[5];
    const float* bo   = (const float*)d_in[6];
    const float* W1   = (const float*)d_in[7];
    const float* b1   = (const float*)d_in[8];
    const float* W2   = (const float*)d_in[9];
    const float* b2   = (const float*)d_in[10];
    const float* ln1g = (const float*)d_in[11];
    const float* ln1b = (const float*)d_in[12];
    const float* ln3g = (const float*)d_in[13];
    const float* ln3b = (const float*)d_in[14];

    float* out = (float*)d_out;                        // (B, C, T) flat
    float* ctx_out = out + (size_t)BQ * CDIM * TLEN;   // (B, 4, 48, C)

    // Workspace layout (floats). Total 38,141,952 floats = 152.6 MB.
    const size_t SZ_ACT = (size_t)BQ * TLEN * CDIM;    // 4,194,304
    const size_t SZ_EXT = (size_t)BQ * EXTL * CDIM;    // 4,390,912
    const size_t SZ_H   = (size_t)BQ * TLEN * FFDIM;   // 16,777,216
    float* ws  = (float*)d_ws;
    float* act = ws;                 // layer activation (B,T,C)
    float* x1b = act + SZ_ACT;       // post-LN1 (B,T,C)
    float* Qb  = x1b + SZ_ACT;       // Q, later x1pre
    float* Kb  = Qb + SZ_ACT;        // K (ext), later x2pre
    float* Vb  = Kb + SZ_EXT;        // V (ext)
    float* Hb  = Vb + SZ_EXT;        // conv tmp / attn O / FF hidden (64 MB)
    float* Ob  = Hb;                 // attention output aliases H region

    const int NT = 16384;            // B*T tokens

    // conv -> (B,C,T) tmp, then transpose to act (B,T,C)
    conv_kernel<<<BQ * CDIM, 256, 0, stream>>>(x, emb, Hb);
    transpose_kernel<<<dim3(TLEN / 32, CDIM / 32, BQ), dim3(32, 8), 0, stream>>>(
        Hb, act, CDIM, TLEN);

    for (int i = 0; i < NLAYER; ++i) {
        const float* Wq = Wqkv + (size_t)i * 3 * CDIM * CDIM;
        const float* Wk = Wq + (size_t)CDIM * CDIM;
        const float* Wv = Wk + (size_t)CDIM * CDIM;
        const float* bq = bqkv + (size_t)i * 3 * CDIM;
        const float* bk = bq + CDIM;
        const float* bv = bk + CDIM;
        const float* Woi = Wo + (size_t)i * CDIM * CDIM;
        const float* boi = bo + (size_t)i * CDIM;
        const float* W1i = W1 + (size_t)i * FFDIM * CDIM;
        const float* b1i = b1 + (size_t)i * FFDIM;
        const float* W2i = W2 + (size_t)i * CDIM * FFDIM;
        const float* b2i = b2 + (size_t)i * CDIM;

        // save per-layer context (last 48 tokens of layer input)
        ctx_copy_kernel<<<(BQ * CTXL * CDIM) / 256, 256, 0, stream>>>(
            act, ctx_out, i);
        // Q = act @ Wq^T + bq   (M=16384, N=256, K=256)
        gemm_kernel<<<dim3(CDIM / 64, NT / 64), 256, 0, stream>>>(
            act, nullptr, 0, i, Wq, bq, nullptr, Qb, NT, CDIM, CDIM, 0);
        // K,V over ext tokens (M=17152)
        gemm_kernel<<<dim3(CDIM / 64, (BQ * EXTL) / 64), 256, 0, stream>>>(
            act, ctx, 1, i, Wk, bk, nullptr, Kb, BQ * EXTL, CDIM, CDIM, 0);
        gemm_kernel<<<dim3(CDIM / 64, (BQ * EXTL) / 64), 256, 0, stream>>>(
            act, ctx, 1, i, Wv, bv, nullptr, Vb, BQ * EXTL, CDIM, CDIM, 0);
        // windowed attention -> O
        attn_kernel<<<dim3(NHEADS, NWIN, BQ), 64, 0, stream>>>(Qb, Kb, Vb, Ob);
        // x1pre = act + O @ Wo^T + bo   (into Qb)
        gemm_kernel<<<dim3(CDIM / 64, NT / 64), 256, 0, stream>>>(
            Ob, nullptr, 0, i, Woi, boi, act, Qb, NT, CDIM, CDIM, 0);
        // x1 = LN1(x1pre)
        ln_kernel<<<NT / 4, 256, 0, stream>>>(Qb, ln1g + i * CDIM,
                                              ln1b + i * CDIM, x1b);
        // H = relu(x1 @ W1^T + b1)   (M=16384, N=1024, K=256)
        gemm_kernel<<<dim3(FFDIM / 64, NT / 64), 256, 0, stream>>>(
            x1b, nullptr, 0, i, W1i, b1i, nullptr, Hb, NT, FFDIM, CDIM, 1);
        // x2pre = x1 + H @ W2^T + b2  (into Kb)
        gemm_kernel<<<dim3(CDIM / 64, NT / 64), 256, 0, stream>>>(
            Hb, nullptr, 0, i, W2i, b2i, x1b, Kb, NT, CDIM, FFDIM, 0);
        // act = LN3(x2pre)
        ln_kernel<<<NT / 4, 256, 0, stream>>>(Kb, ln3g + i * CDIM,
                                              ln3b + i * CDIM, act);
    }

    // final output: act (B,T,C) -> out (B,C,T)
    transpose_kernel<<<dim3(CDIM / 32, TLEN / 32, BQ), dim3(32, 8), 0, stream>>>(
        act, out, TLEN, CDIM);
}

// Round 2
// 1049.337 us; speedup vs baseline: 2.4601x; 2.4601x over previous
//
#include <hip/hip_runtime.h>
#include <math.h>

// Problem constants
#define BQ      16          // batch
#define CDIM    256         // model dim
#define TLEN    1024        // sequence length
#define CTXL    48          // context length
#define CHUNKL  16
#define NLAYER  4
#define NHEADS  8
#define DHEAD   32          // 256/8
#define FFDIM   1024
#define NWIN    64          // T / CHUNK
#define EXTL    1072        // CTX_LEN + T

typedef __attribute__((ext_vector_type(4))) float floatx4;
typedef __attribute__((ext_vector_type(8))) __bf16 bf16x8;

__device__ __forceinline__ unsigned short f2bf(float f) {
    unsigned int u = __float_as_uint(f);
    u += 0x7fff + ((u >> 16) & 1);          // RNE
    return (unsigned short)(u >> 16);
}
__device__ __forceinline__ float bf2f(unsigned short h) {
    return __uint_as_float(((unsigned int)h) << 16);
}

// ---------------------------------------------------------------------------
// fp32 -> bf16 bulk convert (n divisible by 4)
// ---------------------------------------------------------------------------
__global__ void f2b_kernel(const float* __restrict__ in,
                           unsigned short* __restrict__ out, int n) {
    int i = (blockIdx.x * 256 + threadIdx.x) * 4;
    if (i < n) {
        float4 v = *(const float4*)(in + i);
        ushort4 o;
        o.x = f2bf(v.x); o.y = f2bf(v.y); o.z = f2bf(v.z); o.w = f2bf(v.w);
        *(ushort4*)(out + i) = o;
    }
}

// ---------------------------------------------------------------------------
// Depthwise causal conv (fp32 in/out)
// ---------------------------------------------------------------------------
__global__ void conv_kernel(const float* __restrict__ x,
                            const float* __restrict__ emb,
                            float* __restrict__ tmp) {
    int bc = blockIdx.x;
    int b = bc >> 8, c = bc & 255;
    __shared__ float xs[31 + TLEN];
    __shared__ float f[32];
    int t = threadIdx.x;
    if (t < 31) xs[t] = 0.f;
    const float* xrow = x + (size_t)bc * TLEN;
    for (int s = t; s < TLEN; s += 256) xs[31 + s] = xrow[s];
    if (t < 32) {
        const float* e0 = emb + (((size_t)b * 2 + 0) * CDIM + c) * 32;
        const float* e1 = emb + (((size_t)b * 2 + 1) * CDIM + c) * 32;
        f[t] = 0.5f * (e0[t] + e1[t]);
    }
    __syncthreads();
    float* orow = tmp + (size_t)bc * TLEN;
    for (int s = t; s < TLEN; s += 256) {
        float acc = 0.f;
#pragma unroll
        for (int l = 0; l < 32; ++l) acc += f[l] * xs[s + l];
        orow[s] = acc;
    }
}

// ---------------------------------------------------------------------------
// Batched transpose (B,R,S) -> (B,S,R), fp32
// ---------------------------------------------------------------------------
__global__ void transpose_kernel(const float* __restrict__ in,
                                 float* __restrict__ out, int R, int S) {
    __shared__ float tile[32][33];
    int b = blockIdx.z;
    int s0 = blockIdx.x * 32, r0 = blockIdx.y * 32;
    const float* inb = in + (size_t)b * R * S;
    float* outb = out + (size_t)b * R * S;
    int tx = threadIdx.x, ty = threadIdx.y;
    for (int i = ty; i < 32; i += 8)
        tile[i][tx] = inb[(size_t)(r0 + i) * S + s0 + tx];
    __syncthreads();
    for (int i = ty; i < 32; i += 8)
        outb[(size_t)(s0 + i) * R + r0 + tx] = tile[tx][i];
}

// ---------------------------------------------------------------------------
// ctx_out[b][layer][r][c] = act[b][976+r][c]   (fp32)
// ---------------------------------------------------------------------------
__global__ void ctx_copy_kernel(const float* __restrict__ act,
                                float* __restrict__ ctx_out, int layer) {
    int idx = blockIdx.x * 256 + threadIdx.x;
    int c = idx & 255;
    int r = (idx >> 8) % CTXL;
    int b = idx / (CTXL * CDIM);
    ctx_out[(((size_t)b * NLAYER + layer) * CTXL + r) * CDIM + c] =
        act[((size_t)b * TLEN + (TLEN - CTXL) + r) * CDIM + c];
}

// ---------------------------------------------------------------------------
// bf16 MFMA GEMM: out[m][n] = sum_k Arow(m)[k]*W[n][k] + bias[n] (+resid)(relu)
// 128x128 tile, BK=64, 256 threads (4 waves, each 64x64 via 4x4 of 16x16x32).
// Staging: global_load_lds 16B/lane, XOR-swizzled chunks:
//   LDS chunk (m,kc) at index m*8 + (kc ^ (m&7))  -> ds_read_b128 2-way free.
// mode 1 (K/V ext tokens): row -> ctx_bf16 (e<48) or A (act bf16).
// Outputs: fp32 (outf) and/or bf16 (outb); either may be null.
// ---------------------------------------------------------------------------
__global__ __launch_bounds__(256) void gemm_bf16_kernel(
    const unsigned short* __restrict__ A,
    const unsigned short* __restrict__ ctxb,
    int mode, int layer,
    const unsigned short* __restrict__ W,
    const float* __restrict__ bias,
    const float* __restrict__ resid,
    float* __restrict__ outf,
    unsigned short* __restrict__ outb,
    int M, int N, int K, int relu) {
    __shared__ __align__(16) char smem[32768];
    char* smemA = smem;
    char* smemB = smem + 16384;
    int tid = threadIdx.x;
    int lane = tid & 63;
    int wid = tid >> 6;
    int ln = lane & 15, kq = lane >> 4;
    int wm = (wid >> 1) * 64, wn = (wid & 1) * 64;
    int m0 = blockIdx.y * 128, n0 = blockIdx.x * 128;

    // per-issue staging row pointers (k-invariant)
    const unsigned short* arow[4];
    const unsigned short* brow[4];
    int kcof[4];
#pragma unroll
    for (int is = 0; is < 4; ++is) {
        int q = tid + is * 256;
        int m = q >> 3;
        int kc = (q & 7) ^ (m & 7);
        kcof[is] = kc * 8;
        int mg = m0 + m;
        if (mode == 0) {
            arow[is] = A + (size_t)mg * K;
        } else {
            int b = mg / EXTL;
            int e = mg - b * EXTL;
            arow[is] = (e < CTXL)
                ? ctxb + (((size_t)b * NLAYER + layer) * CTXL + e) * CDIM
                : A + ((size_t)b * TLEN + (e - CTXL)) * CDIM;
        }
        brow[is] = W + (size_t)(n0 + m) * K;
    }

    floatx4 acc[4][4];
#pragma unroll
    for (int i = 0; i < 4; ++i)
#pragma unroll
        for (int j = 0; j < 4; ++j) acc[i][j] = (floatx4){0.f, 0.f, 0.f, 0.f};

    for (int kt = 0; kt < K; kt += 64) {
#pragma unroll
        for (int is = 0; is < 4; ++is) {
            int off = (is * 256 + tid) * 16;
            __builtin_amdgcn_global_load_lds(
                (const __attribute__((address_space(1))) unsigned int*)
                    (const void*)(arow[is] + kt + kcof[is]),
                (__attribute__((address_space(3))) unsigned int*)
                    (void*)(smemA + off), 16, 0, 0);
            __builtin_amdgcn_global_load_lds(
                (const __attribute__((address_space(1))) unsigned int*)
                    (const void*)(brow[is] + kt + kcof[is]),
                (__attribute__((address_space(3))) unsigned int*)
                    (void*)(smemB + off), 16, 0, 0);
        }
        __syncthreads();
#pragma unroll
        for (int s = 0; s < 2; ++s) {
            bf16x8 af[4], bfv[4];
#pragma unroll
            for (int i = 0; i < 4; ++i) {
                int ml = wm + 16 * i + ln;
                int kc = s * 4 + kq;
                af[i] = *(const bf16x8*)(smemA + (ml * 8 + (kc ^ (ml & 7))) * 16);
                int nl = wn + 16 * i + ln;
                bfv[i] = *(const bf16x8*)(smemB + (nl * 8 + (kc ^ (nl & 7))) * 16);
            }
#pragma unroll
            for (int i = 0; i < 4; ++i)
#pragma unroll
                for (int j = 0; j < 4; ++j)
                    acc[i][j] = __builtin_amdgcn_mfma_f32_16x16x32_bf16(
                        af[i], bfv[j], acc[i][j], 0, 0, 0);
        }
        __syncthreads();
    }

    // epilogue: D element (m=(lane>>4)*4+reg, n=lane&15) within each 16x16 tile
#pragma unroll
    for (int i = 0; i < 4; ++i) {
#pragma unroll
        for (int r = 0; r < 4; ++r) {
            int m = m0 + wm + 16 * i + kq * 4 + r;
#pragma unroll
            for (int j = 0; j < 4; ++j) {
                int n = n0 + wn + 16 * j + ln;
                float v = acc[i][j][r] + bias[n];
                if (resid) v += resid[(size_t)m * N + n];
                if (relu) v = fmaxf(v, 0.f);
                if (outf) outf[(size_t)m * N + n] = v;
                if (outb) outb[(size_t)m * N + n] = f2bf(v);
            }
        }
    }
}

// ---------------------------------------------------------------------------
// Windowed attention, one wave per (head, window, batch). bf16 in/out,
// fp32 math in LDS.
// ---------------------------------------------------------------------------
__global__ void attn_kernel(const unsigned short* __restrict__ Q,
                            const unsigned short* __restrict__ K,
                            const unsigned short* __restrict__ V,
                            unsigned short* __restrict__ O) {
    int h = blockIdx.x, n = blockIdx.y, b = blockIdx.z;
    __shared__ float qs[16][33];
    __shared__ float ks[64][33];
    __shared__ float vs[64][33];
    __shared__ float ss[16][65];
    int t = threadIdx.x;   // 0..63
    const unsigned short* Qb = Q + ((size_t)b * TLEN + n * CHUNKL) * CDIM + h * DHEAD;
    const unsigned short* Kb = K + ((size_t)b * EXTL + n * CHUNKL) * CDIM + h * DHEAD;
    const unsigned short* Vb = V + ((size_t)b * EXTL + n * CHUNKL) * CDIM + h * DHEAD;
#pragma unroll
    for (int s = 0; s < 8; ++s) {
        int idx = t + s * 64;
        int r = idx >> 5, d = idx & 31;
        qs[r][d] = bf2f(Qb[(size_t)r * CDIM + d]);
    }
#pragma unroll
    for (int s = 0; s < 32; ++s) {
        int idx = t + s * 64;
        int r = idx >> 5, d = idx & 31;
        ks[r][d] = bf2f(Kb[(size_t)r * CDIM + d]);
        vs[r][d] = bf2f(Vb[(size_t)r * CDIM + d]);
    }
    __syncthreads();
    const float scale = 0.17677669529663687f;  // 1/sqrt(32)
    int w = t;
    for (int r = 0; r < 16; ++r) {
        float acc = 0.f;
#pragma unroll
        for (int d = 0; d < 32; ++d) acc += qs[r][d] * ks[w][d];
        ss[r][w] = acc * scale;
    }
    __syncthreads();
    if (t < 16) {
        float m = -1e30f;
        for (int w2 = 0; w2 < 64; ++w2) m = fmaxf(m, ss[t][w2]);
        float sum = 0.f;
        for (int w2 = 0; w2 < 64; ++w2) {
            float e = __expf(ss[t][w2] - m);
            ss[t][w2] = e;
            sum += e;
        }
        float inv = 1.f / sum;
        for (int w2 = 0; w2 < 64; ++w2) ss[t][w2] *= inv;
    }
    __syncthreads();
    int d = t & 31, r0 = t >> 5;
    unsigned short* Ob = O + ((size_t)b * TLEN + n * CHUNKL) * CDIM + h * DHEAD;
    for (int r = r0; r < 16; r += 2) {
        float acc = 0.f;
#pragma unroll
        for (int w2 = 0; w2 < 64; ++w2) acc += ss[r][w2] * vs[w2][d];
        Ob[(size_t)r * CDIM + d] = f2bf(acc);
    }
}

// ---------------------------------------------------------------------------
// LayerNorm over C=256 (fp32 in, fp32 + bf16 out), one wave per token.
// ---------------------------------------------------------------------------
__global__ void ln_kernel(const float* __restrict__ pre,
                          const float* __restrict__ g,
                          const float* __restrict__ beta,
                          float* __restrict__ out,
                          unsigned short* __restrict__ outb) {
    int tok = blockIdx.x * 4 + (threadIdx.x >> 6);
    int lane = threadIdx.x & 63;
    const float* p = pre + (size_t)tok * CDIM;
    float v[4];
    float s1 = 0.f, s2 = 0.f;
#pragma unroll
    for (int j = 0; j < 4; ++j) {
        float x = p[lane + 64 * j];
        v[j] = x;
        s1 += x;
        s2 += x * x;
    }
#pragma unroll
    for (int off = 32; off >= 1; off >>= 1) {
        s1 += __shfl_xor(s1, off, 64);
        s2 += __shfl_xor(s2, off, 64);
    }
    float mu = s1 * (1.f / 256.f);
    float var = s2 * (1.f / 256.f) - mu * mu;
    float inv = rsqrtf(var + 1e-5f);
    float* o = out + (size_t)tok * CDIM;
    unsigned short* ob = outb + (size_t)tok * CDIM;
#pragma unroll
    for (int j = 0; j < 4; ++j) {
        int c = lane + 64 * j;
        float y = (v[j] - mu) * inv * g[c] + beta[c];
        o[c] = y;
        ob[c] = f2bf(y);
    }
}

// ---------------------------------------------------------------------------
extern "C" void kernel_launch(void* const* d_in, const int* in_sizes, int n_in,
                              void* d_out, int out_size, void* d_ws, size_t ws_size,
                              hipStream_t stream) {
    const float* x    = (const float*)d_in[0];
    const float* emb  = (const float*)d_in[1];
    const float* ctx  = (const float*)d_in[2];
    const float* Wqkv = (const float*)d_in[3];
    const float* bqkv = (const float*)d_in[4];
    const float* Wo   = (const float*)d_in[5];
    const float* bo   = (const float*)d_in[6];
    const float* W1   = (const float*)d_in[7];
    const float* b1   = (const float*)d_in[8];
    const float* W2   = (const float*)d_in[9];
    const float* b2   = (const float*)d_in[10];
    const float* ln1g = (const float*)d_in[11];
    const float* ln1b = (const float*)d_in[12];
    const float* ln3g = (const float*)d_in[13];
    const float* ln3b = (const float*)d_in[14];

    float* out = (float*)d_out;                        // (B, C, T)
    float* ctx_out = out + (size_t)BQ * CDIM * TLEN;   // (B, 4, 48, C)

    // Workspace layout (bytes, total ~142.9 MB)
    char* w = (char*)d_ws;
    float* act  = (float*)w;          w += 16777216;   // (B,T,C) fp32
    float* x1b  = (float*)w;          w += 16777216;   // post-LN1 fp32
    float* pre  = (float*)w;          w += 16777216;   // pre-LN scratch / conv tmp
    unsigned short* actbf = (unsigned short*)w;  w += 8388608;
    unsigned short* x1bf  = (unsigned short*)w;  w += 8388608;
    unsigned short* Qbf   = (unsigned short*)w;  w += 8388608;
    unsigned short* Obf   = (unsigned short*)w;  w += 8388608;
    unsigned short* Kbf   = (unsigned short*)w;  w += 8781824;   // (B,1072,C)
    unsigned short* Vbf   = (unsigned short*)w;  w += 8781824;
    unsigned short* Hbf   = (unsigned short*)w;  w += 33554432;  // (B,T,FF)
    unsigned short* ctxbf  = (unsigned short*)w; w += 1572864;
    unsigned short* Wqkvbf = (unsigned short*)w; w += 1572864;
    unsigned short* Wobf   = (unsigned short*)w; w += 524288;
    unsigned short* W1bf   = (unsigned short*)w; w += 2097152;
    unsigned short* W2bf   = (unsigned short*)w; w += 2097152;

    const int NT = BQ * TLEN;   // 16384

    // weight / ctx conversions to bf16
    f2b_kernel<<<768, 256, 0, stream>>>(Wqkv, Wqkvbf, NLAYER * 3 * CDIM * CDIM);
    f2b_kernel<<<256, 256, 0, stream>>>(Wo, Wobf, NLAYER * CDIM * CDIM);
    f2b_kernel<<<1024, 256, 0, stream>>>(W1, W1bf, NLAYER * FFDIM * CDIM);
    f2b_kernel<<<1024, 256, 0, stream>>>(W2, W2bf, NLAYER * CDIM * FFDIM);
    f2b_kernel<<<768, 256, 0, stream>>>(ctx, ctxbf, BQ * NLAYER * CTXL * CDIM);

    // conv -> pre (B,C,T), transpose -> act (B,T,C), bf16 shadow
    conv_kernel<<<BQ * CDIM, 256, 0, stream>>>(x, emb, pre);
    transpose_kernel<<<dim3(TLEN / 32, CDIM / 32, BQ), dim3(32, 8), 0, stream>>>(
        pre, act, CDIM, TLEN);
    f2b_kernel<<<4096, 256, 0, stream>>>(act, actbf, NT * CDIM);

    for (int i = 0; i < NLAYER; ++i) {
        const unsigned short* Wqb = Wqkvbf + (size_t)i * 3 * CDIM * CDIM;
        const unsigned short* Wkb = Wqb + (size_t)CDIM * CDIM;
        const unsigned short* Wvb = Wkb + (size_t)CDIM * CDIM;
        const float* bq = bqkv + (size_t)i * 3 * CDIM;
        const float* bk = bq + CDIM;
        const float* bv = bk + CDIM;
        const unsigned short* Wob = Wobf + (size_t)i * CDIM * CDIM;
        const float* boi = bo + (size_t)i * CDIM;
        const unsigned short* W1b = W1bf + (size_t)i * FFDIM * CDIM;
        const float* b1i = b1 + (size_t)i * FFDIM;
        const unsigned short* W2b = W2bf + (size_t)i * CDIM * FFDIM;
        const float* b2i = b2 + (size_t)i * CDIM;

        ctx_copy_kernel<<<(BQ * CTXL * CDIM) / 256, 256, 0, stream>>>(
            act, ctx_out, i);
        // Q (bf16 out only)
        gemm_bf16_kernel<<<dim3(2, 128), 256, 0, stream>>>(
            actbf, nullptr, 0, i, Wqb, bq, nullptr, nullptr, Qbf,
            NT, CDIM, CDIM, 0);
        // K, V over ext tokens (M=17152)
        gemm_bf16_kernel<<<dim3(2, 134), 256, 0, stream>>>(
            actbf, ctxbf, 1, i, Wkb, bk, nullptr, nullptr, Kbf,
            BQ * EXTL, CDIM, CDIM, 0);
        gemm_bf16_kernel<<<dim3(2, 134), 256, 0, stream>>>(
            actbf, ctxbf, 1, i, Wvb, bv, nullptr, nullptr, Vbf,
            BQ * EXTL, CDIM, CDIM, 0);
        // attention -> Obf
        attn_kernel<<<dim3(NHEADS, NWIN, BQ), 64, 0, stream>>>(Qbf, Kbf, Vbf, Obf);
        // x1pre = act + O@Wo^T + bo -> pre (fp32)
        gemm_bf16_kernel<<<dim3(2, 128), 256, 0, stream>>>(
            Obf, nullptr, 0, i, Wob, boi, act, pre, nullptr,
            NT, CDIM, CDIM, 0);
        // x1 = LN1(pre) -> x1b fp32 + x1bf
        ln_kernel<<<NT / 4, 256, 0, stream>>>(pre, ln1g + i * CDIM,
                                              ln1b + i * CDIM, x1b, x1bf);
        // H = relu(x1@W1^T + b1) -> Hbf (bf16 only)
        gemm_bf16_kernel<<<dim3(8, 128), 256, 0, stream>>>(
            x1bf, nullptr, 0, i, W1b, b1i, nullptr, nullptr, Hbf,
            NT, FFDIM, CDIM, 1);
        // x2pre = x1 + H@W2^T + b2 -> pre (fp32)
        gemm_bf16_kernel<<<dim3(2, 128), 256, 0, stream>>>(
            Hbf, nullptr, 0, i, W2b, b2i, x1b, pre, nullptr,
            NT, CDIM, FFDIM, 0);
        // act = LN3(pre) -> act fp32 + actbf
        ln_kernel<<<NT / 4, 256, 0, stream>>>(pre, ln3g + i * CDIM,
                                              ln3b + i * CDIM, act, actbf);
    }

    // final output: act (B,T,C) -> out (B,C,T)
    transpose_kernel<<<dim3(CDIM / 32, TLEN / 32, BQ), dim3(32, 8), 0, stream>>>(
        act, out, TLEN, CDIM);
}

// Round 3
// 661.627 us; speedup vs baseline: 3.9017x; 1.5860x over previous
//
#include <hip/hip_runtime.h>
#include <math.h>

// Problem constants
#define BQ      16          // batch
#define CDIM    256         // model dim
#define TLEN    1024        // sequence length
#define CTXL    48          // context length
#define CHUNKL  16
#define NLAYER  4
#define NHEADS  8
#define DHEAD   32          // 256/8
#define FFDIM   1024
#define NWIN    64          // T / CHUNK
#define EXTL    1072        // CTX_LEN + T
#define QKV_N   768

typedef __attribute__((ext_vector_type(4))) float floatx4;
typedef __attribute__((ext_vector_type(8))) __bf16 bf16x8;

__device__ __forceinline__ unsigned short f2bf(float f) {
    unsigned int u = __float_as_uint(f);
    u += 0x7fff + ((u >> 16) & 1);          // RNE
    return (unsigned short)(u >> 16);
}
__device__ __forceinline__ float bf2f(unsigned short h) {
    return __uint_as_float(((unsigned int)h) << 16);
}

// ---------------------------------------------------------------------------
// fp32 -> bf16 bulk convert (n divisible by 4)
// ---------------------------------------------------------------------------
__global__ void f2b_kernel(const float* __restrict__ in,
                           unsigned short* __restrict__ out, int n) {
    int i = (blockIdx.x * 256 + threadIdx.x) * 4;
    if (i < n) {
        float4 v = *(const float4*)(in + i);
        ushort4 o;
        o.x = f2bf(v.x); o.y = f2bf(v.y); o.z = f2bf(v.z); o.w = f2bf(v.w);
        *(ushort4*)(out + i) = o;
    }
}

// ---------------------------------------------------------------------------
// Depthwise causal conv (fp32 in/out)
// ---------------------------------------------------------------------------
__global__ void conv_kernel(const float* __restrict__ x,
                            const float* __restrict__ emb,
                            float* __restrict__ tmp) {
    int bc = blockIdx.x;
    int b = bc >> 8, c = bc & 255;
    __shared__ float xs[31 + TLEN];
    __shared__ float f[32];
    int t = threadIdx.x;
    if (t < 31) xs[t] = 0.f;
    const float* xrow = x + (size_t)bc * TLEN;
    for (int s = t; s < TLEN; s += 256) xs[31 + s] = xrow[s];
    if (t < 32) {
        const float* e0 = emb + (((size_t)b * 2 + 0) * CDIM + c) * 32;
        const float* e1 = emb + (((size_t)b * 2 + 1) * CDIM + c) * 32;
        f[t] = 0.5f * (e0[t] + e1[t]);
    }
    __syncthreads();
    float* orow = tmp + (size_t)bc * TLEN;
    for (int s = t; s < TLEN; s += 256) {
        float acc = 0.f;
#pragma unroll
        for (int l = 0; l < 32; ++l) acc += f[l] * xs[s + l];
        orow[s] = acc;
    }
}

// ---------------------------------------------------------------------------
// Batched transpose (B,R,S) -> (B,S,R), fp32 out + optional bf16 shadow
// ---------------------------------------------------------------------------
__global__ void transpose_kernel(const float* __restrict__ in,
                                 float* __restrict__ out,
                                 unsigned short* __restrict__ outb,
                                 int R, int S) {
    __shared__ float tile[32][33];
    int b = blockIdx.z;
    int s0 = blockIdx.x * 32, r0 = blockIdx.y * 32;
    const float* inb = in + (size_t)b * R * S;
    float* outb32 = out + (size_t)b * R * S;
    int tx = threadIdx.x, ty = threadIdx.y;
    for (int i = ty; i < 32; i += 8)
        tile[i][tx] = inb[(size_t)(r0 + i) * S + s0 + tx];
    __syncthreads();
    for (int i = ty; i < 32; i += 8) {
        float v = tile[tx][i];
        size_t idx = (size_t)(s0 + i) * R + r0 + tx;
        outb32[idx] = v;
        if (outb) outb[(size_t)b * R * S + idx] = f2bf(v);
    }
}

// ---------------------------------------------------------------------------
// ctx_out[b][layer][r][c] = act[b][976+r][c]   (fp32)
// ---------------------------------------------------------------------------
__global__ void ctx_copy_kernel(const float* __restrict__ act,
                                float* __restrict__ ctx_out, int layer) {
    int idx = blockIdx.x * 256 + threadIdx.x;
    int c = idx & 255;
    int r = (idx >> 8) % CTXL;
    int b = idx / (CTXL * CDIM);
    ctx_out[(((size_t)b * NLAYER + layer) * CTXL + r) * CDIM + c] =
        act[((size_t)b * TLEN + (TLEN - CTXL) + r) * CDIM + c];
}

// ---------------------------------------------------------------------------
// bf16 MFMA GEMM (templated tile): out[m][n] = sum_k Arow(m)[k]*W[n][k]
//   + bias[n] (+resid)(relu). BK=64, 256 threads.
// BM x BN block tile; each wave WM x WN. Staging via global_load_lds 16B,
// XOR-swizzled chunks: chunk (row,kc) at row*8 + (kc ^ (row&7)).
// mode 1 (ext tokens): row -> ctxb (e<48) or A (e-48).
// ---------------------------------------------------------------------------
template<int BM, int BN, int WM, int WN>
__global__ __launch_bounds__(256) void gemm_bf16_kernel(
    const unsigned short* __restrict__ A,
    const unsigned short* __restrict__ ctxb,
    int mode, int layer,
    const unsigned short* __restrict__ W,
    const float* __restrict__ bias,
    const float* __restrict__ resid,
    float* __restrict__ outf,
    unsigned short* __restrict__ outb,
    int M, int N, int K, int relu) {
    constexpr int IA = BM / 32;
    constexpr int IB = BN / 32;
    constexpr int MT = WM / 16;
    constexpr int NTT = WN / 16;
    constexpr int NWX = BN / WN;
    __shared__ __align__(16) char smem[(BM + BN) * 128];
    char* smemA = smem;
    char* smemB = smem + BM * 128;
    int tid = threadIdx.x;
    int lane = tid & 63;
    int wid = tid >> 6;
    int ln = lane & 15, kq = lane >> 4;
    int wm = (wid / NWX) * WM, wn = (wid % NWX) * WN;
    int m0 = blockIdx.y * BM, n0 = blockIdx.x * BN;

    const unsigned short* arow[IA];
    int akc[IA];
    const unsigned short* brow[IB];
    int bkc[IB];
#pragma unroll
    for (int is = 0; is < IA; ++is) {
        int q = tid + is * 256;
        int m = q >> 3;
        akc[is] = ((q & 7) ^ (m & 7)) * 8;
        int mg = m0 + m;
        if (mode == 0) {
            arow[is] = A + (size_t)mg * K;
        } else {
            int b = mg / EXTL;
            int e = mg - b * EXTL;
            arow[is] = (e < CTXL)
                ? ctxb + (((size_t)b * NLAYER + layer) * CTXL + e) * CDIM
                : A + ((size_t)b * TLEN + (e - CTXL)) * CDIM;
        }
    }
#pragma unroll
    for (int is = 0; is < IB; ++is) {
        int q = tid + is * 256;
        int m = q >> 3;
        bkc[is] = ((q & 7) ^ (m & 7)) * 8;
        brow[is] = W + (size_t)(n0 + m) * K;
    }

    floatx4 acc[MT][NTT];
#pragma unroll
    for (int i = 0; i < MT; ++i)
#pragma unroll
        for (int j = 0; j < NTT; ++j) acc[i][j] = (floatx4){0.f, 0.f, 0.f, 0.f};

    for (int kt = 0; kt < K; kt += 64) {
#pragma unroll
        for (int is = 0; is < IA; ++is) {
            int off = (is * 256 + tid) * 16;
            __builtin_amdgcn_global_load_lds(
                (const __attribute__((address_space(1))) unsigned int*)
                    (const void*)(arow[is] + kt + akc[is]),
                (__attribute__((address_space(3))) unsigned int*)
                    (void*)(smemA + off), 16, 0, 0);
        }
#pragma unroll
        for (int is = 0; is < IB; ++is) {
            int off = (is * 256 + tid) * 16;
            __builtin_amdgcn_global_load_lds(
                (const __attribute__((address_space(1))) unsigned int*)
                    (const void*)(brow[is] + kt + bkc[is]),
                (__attribute__((address_space(3))) unsigned int*)
                    (void*)(smemB + off), 16, 0, 0);
        }
        __syncthreads();
#pragma unroll
        for (int s = 0; s < 2; ++s) {
            bf16x8 af[MT], bfv[NTT];
            int kc = s * 4 + kq;
#pragma unroll
            for (int i = 0; i < MT; ++i) {
                int ml = wm + 16 * i + ln;
                af[i] = *(const bf16x8*)(smemA + (ml * 8 + (kc ^ (ml & 7))) * 16);
            }
#pragma unroll
            for (int j = 0; j < NTT; ++j) {
                int nl = wn + 16 * j + ln;
                bfv[j] = *(const bf16x8*)(smemB + (nl * 8 + (kc ^ (nl & 7))) * 16);
            }
#pragma unroll
            for (int i = 0; i < MT; ++i)
#pragma unroll
                for (int j = 0; j < NTT; ++j)
                    acc[i][j] = __builtin_amdgcn_mfma_f32_16x16x32_bf16(
                        af[i], bfv[j], acc[i][j], 0, 0, 0);
        }
        __syncthreads();
    }

#pragma unroll
    for (int i = 0; i < MT; ++i) {
#pragma unroll
        for (int r = 0; r < 4; ++r) {
            int m = m0 + wm + 16 * i + kq * 4 + r;
#pragma unroll
            for (int j = 0; j < NTT; ++j) {
                int n = n0 + wn + 16 * j + ln;
                float v = acc[i][j][r] + bias[n];
                if (resid) v += resid[(size_t)m * N + n];
                if (relu) v = fmaxf(v, 0.f);
                if (outf) outf[(size_t)m * N + n] = v;
                if (outb) outb[(size_t)m * N + n] = f2bf(v);
            }
        }
    }
}

// ---------------------------------------------------------------------------
// MFMA windowed attention. One block (256 thr, 4 waves) per (window, batch);
// each wave handles 2 heads. QKV: (B, EXTL, 768) bf16 [Q|K|V sections].
// Q/K fragments direct from global; V staged transposed in LDS (shared by
// all heads); P round-trips through per-wave LDS (C-layout -> A-layout).
// ---------------------------------------------------------------------------
__global__ __launch_bounds__(256) void attn_mfma_kernel(
    const unsigned short* __restrict__ QKV,
    unsigned short* __restrict__ O) {
    int n = blockIdx.x, b = blockIdx.y;
    __shared__ __align__(16) unsigned short Vt[256][72];      // V^T [d][key]
    __shared__ __align__(16) unsigned short Pb[4][16][72];    // per-wave P
    int tid = threadIdx.x;
    int lane = tid & 63, wid = tid >> 6;
    int ln = lane & 15, quad = lane >> 4;
    int key0 = n * CHUNKL;
    const unsigned short* base = QKV + (size_t)b * EXTL * QKV_N;

    // stage V^T: V[key][d] -> Vt[d][key]
    {
        int row = tid >> 2;              // key 0..63
        int c0 = (tid & 3) * 64;         // d block
        const unsigned short* vrow =
            base + (size_t)(key0 + row) * QKV_N + 512 + c0;
#pragma unroll
        for (int s = 0; s < 8; ++s) {
            bf16x8 v = *(const bf16x8*)(vrow + 8 * s);
#pragma unroll
            for (int j = 0; j < 8; ++j)
                Vt[c0 + 8 * s + j][row] = ((const unsigned short*)&v)[j];
        }
    }
    __syncthreads();

    const float scale = 0.17677669529663687f;   // 1/sqrt(32)
#pragma unroll
    for (int hh = 0; hh < 2; ++hh) {
        int h = wid * 2 + hh;
        // Q A-frag: A[m=ln][k=quad*8+j]
        bf16x8 qf = *(const bf16x8*)(base
            + (size_t)(CTXL + key0 + ln) * QKV_N + h * DHEAD + quad * 8);
        floatx4 sc[4];
#pragma unroll
        for (int j = 0; j < 4; ++j) {
            // K B-frag: B[n=key ln][k=quad*8+..]
            bf16x8 kf = *(const bf16x8*)(base
                + (size_t)(key0 + j * 16 + ln) * QKV_N + 256
                + h * DHEAD + quad * 8);
            sc[j] = __builtin_amdgcn_mfma_f32_16x16x32_bf16(
                qf, kf, (floatx4){0.f, 0.f, 0.f, 0.f}, 0, 0, 0);
        }
        // softmax per row q = quad*4+r across 64 keys (4 regs x 16 lanes)
        float p[4][4];
#pragma unroll
        for (int r = 0; r < 4; ++r) {
            float mx = -1e30f;
#pragma unroll
            for (int j = 0; j < 4; ++j) mx = fmaxf(mx, sc[j][r]);
            mx = fmaxf(mx, __shfl_xor(mx, 1, 64));
            mx = fmaxf(mx, __shfl_xor(mx, 2, 64));
            mx = fmaxf(mx, __shfl_xor(mx, 4, 64));
            mx = fmaxf(mx, __shfl_xor(mx, 8, 64));
            float sum = 0.f;
#pragma unroll
            for (int j = 0; j < 4; ++j) {
                float e = __expf((sc[j][r] - mx) * scale);
                p[r][j] = e;
                sum += e;
            }
            sum += __shfl_xor(sum, 1, 64);
            sum += __shfl_xor(sum, 2, 64);
            sum += __shfl_xor(sum, 4, 64);
            sum += __shfl_xor(sum, 8, 64);
            float inv = 1.f / sum;
#pragma unroll
            for (int j = 0; j < 4; ++j) p[r][j] *= inv;
        }
        // P (C-layout) -> per-wave LDS [q][key]
#pragma unroll
        for (int r = 0; r < 4; ++r)
#pragma unroll
            for (int j = 0; j < 4; ++j)
                Pb[wid][quad * 4 + r][j * 16 + ln] = f2bf(p[r][j]);
        // PV: A-frags of P, B-frags of V^T  (same-wave DS ops are ordered)
        bf16x8 pa0 = *(const bf16x8*)&Pb[wid][ln][quad * 8];
        bf16x8 pa1 = *(const bf16x8*)&Pb[wid][ln][32 + quad * 8];
        floatx4 o[2];
#pragma unroll
        for (int jt = 0; jt < 2; ++jt) {
            bf16x8 v0 = *(const bf16x8*)&Vt[h * DHEAD + jt * 16 + ln][quad * 8];
            bf16x8 v1 = *(const bf16x8*)&Vt[h * DHEAD + jt * 16 + ln][32 + quad * 8];
            floatx4 a = __builtin_amdgcn_mfma_f32_16x16x32_bf16(
                pa0, v0, (floatx4){0.f, 0.f, 0.f, 0.f}, 0, 0, 0);
            o[jt] = __builtin_amdgcn_mfma_f32_16x16x32_bf16(pa1, v1, a, 0, 0, 0);
        }
        unsigned short* Ob =
            O + ((size_t)b * TLEN + n * CHUNKL) * CDIM + h * DHEAD;
#pragma unroll
        for (int jt = 0; jt < 2; ++jt)
#pragma unroll
            for (int r = 0; r < 4; ++r)
                Ob[(size_t)(quad * 4 + r) * CDIM + jt * 16 + ln] = f2bf(o[jt][r]);
    }
}

// ---------------------------------------------------------------------------
// LayerNorm over C=256 (fp32 in, fp32 + bf16 out), one wave per token.
// ---------------------------------------------------------------------------
__global__ void ln_kernel(const float* __restrict__ pre,
                          const float* __restrict__ g,
                          const float* __restrict__ beta,
                          float* __restrict__ out,
                          unsigned short* __restrict__ outb) {
    int tok = blockIdx.x * 4 + (threadIdx.x >> 6);
    int lane = threadIdx.x & 63;
    const float* p = pre + (size_t)tok * CDIM;
    float v[4];
    float s1 = 0.f, s2 = 0.f;
#pragma unroll
    for (int j = 0; j < 4; ++j) {
        float x = p[lane + 64 * j];
        v[j] = x;
        s1 += x;
        s2 += x * x;
    }
#pragma unroll
    for (int off = 32; off >= 1; off >>= 1) {
        s1 += __shfl_xor(s1, off, 64);
        s2 += __shfl_xor(s2, off, 64);
    }
    float mu = s1 * (1.f / 256.f);
    float var = s2 * (1.f / 256.f) - mu * mu;
    float inv = rsqrtf(var + 1e-5f);
    float* o = out + (size_t)tok * CDIM;
    unsigned short* ob = outb + (size_t)tok * CDIM;
#pragma unroll
    for (int j = 0; j < 4; ++j) {
        int c = lane + 64 * j;
        float y = (v[j] - mu) * inv * g[c] + beta[c];
        o[c] = y;
        ob[c] = f2bf(y);
    }
}

// ---------------------------------------------------------------------------
extern "C" void kernel_launch(void* const* d_in, const int* in_sizes, int n_in,
                              void* d_out, int out_size, void* d_ws, size_t ws_size,
                              hipStream_t stream) {
    const float* x    = (const float*)d_in[0];
    const float* emb  = (const float*)d_in[1];
    const float* ctx  = (const float*)d_in[2];
    const float* Wqkv = (const float*)d_in[3];
    const float* bqkv = (const float*)d_in[4];
    const float* Wo   = (const float*)d_in[5];
    const float* bo   = (const float*)d_in[6];
    const float* W1   = (const float*)d_in[7];
    const float* b1   = (const float*)d_in[8];
    const float* W2   = (const float*)d_in[9];
    const float* b2   = (const float*)d_in[10];
    const float* ln1g = (const float*)d_in[11];
    const float* ln1b = (const float*)d_in[12];
    const float* ln3g = (const float*)d_in[13];
    const float* ln3b = (const float*)d_in[14];

    float* out = (float*)d_out;                        // (B, C, T)
    float* ctx_out = out + (size_t)BQ * CDIM * TLEN;   // (B, 4, 48, C)

    // Workspace layout (bytes, total ~141.3 MB)
    char* w = (char*)d_ws;
    float* act  = (float*)w;          w += 16777216;   // (B,T,C) fp32
    float* x1b  = (float*)w;          w += 16777216;   // post-LN1 fp32
    float* pre  = (float*)w;          w += 16777216;   // pre-LN / conv tmp
    unsigned short* actbf  = (unsigned short*)w; w += 8388608;
    unsigned short* x1bf   = (unsigned short*)w; w += 8388608;
    unsigned short* Obf    = (unsigned short*)w; w += 8388608;
    unsigned short* QKVbf  = (unsigned short*)w; w += 26345472;  // (B,1072,768)
    unsigned short* Hbf    = (unsigned short*)w; w += 33554432;  // (B,T,FF)
    unsigned short* ctxbf  = (unsigned short*)w; w += 1572864;
    unsigned short* Wqkvbf = (unsigned short*)w; w += 1572864;
    unsigned short* Wobf   = (unsigned short*)w; w += 524288;
    unsigned short* W1bf   = (unsigned short*)w; w += 2097152;
    unsigned short* W2bf   = (unsigned short*)w; w += 2097152;

    const int NT = BQ * TLEN;   // 16384

    // weight / ctx conversions to bf16
    f2b_kernel<<<768, 256, 0, stream>>>(Wqkv, Wqkvbf, NLAYER * 3 * CDIM * CDIM);
    f2b_kernel<<<256, 256, 0, stream>>>(Wo, Wobf, NLAYER * CDIM * CDIM);
    f2b_kernel<<<1024, 256, 0, stream>>>(W1, W1bf, NLAYER * FFDIM * CDIM);
    f2b_kernel<<<1024, 256, 0, stream>>>(W2, W2bf, NLAYER * CDIM * FFDIM);
    f2b_kernel<<<768, 256, 0, stream>>>(ctx, ctxbf, BQ * NLAYER * CTXL * CDIM);

    // conv -> pre (B,C,T), transpose -> act (B,T,C) fp32 + bf16
    conv_kernel<<<BQ * CDIM, 256, 0, stream>>>(x, emb, pre);
    transpose_kernel<<<dim3(TLEN / 32, CDIM / 32, BQ), dim3(32, 8), 0, stream>>>(
        pre, act, actbf, CDIM, TLEN);

    for (int i = 0; i < NLAYER; ++i) {
        const unsigned short* Wqkvb = Wqkvbf + (size_t)i * 3 * CDIM * CDIM;
        const float* bqi = bqkv + (size_t)i * 3 * CDIM;
        const unsigned short* Wob = Wobf + (size_t)i * CDIM * CDIM;
        const float* boi = bo + (size_t)i * CDIM;
        const unsigned short* W1b = W1bf + (size_t)i * FFDIM * CDIM;
        const float* b1i = b1 + (size_t)i * FFDIM;
        const unsigned short* W2b = W2bf + (size_t)i * CDIM * FFDIM;
        const float* b2i = b2 + (size_t)i * CDIM;

        ctx_copy_kernel<<<(BQ * CTXL * CDIM) / 256, 256, 0, stream>>>(
            act, ctx_out, i);
        // QKV = [ctx|act] @ Wqkv^T + bqkv  (M=17152, N=768, K=256)
        gemm_bf16_kernel<128, 128, 64, 64><<<dim3(6, 134), 256, 0, stream>>>(
            actbf, ctxbf, 1, i, Wqkvb, bqi, nullptr, nullptr, QKVbf,
            BQ * EXTL, QKV_N, CDIM, 0);
        // attention -> Obf
        attn_mfma_kernel<<<dim3(NWIN, BQ), 256, 0, stream>>>(QKVbf, Obf);
        // x1pre = act + O@Wo^T + bo -> pre (fp32)
        gemm_bf16_kernel<64, 128, 64, 32><<<dim3(2, 256), 256, 0, stream>>>(
            Obf, nullptr, 0, i, Wob, boi, act, pre, nullptr,
            NT, CDIM, CDIM, 0);
        // x1 = LN1(pre)
        ln_kernel<<<NT / 4, 256, 0, stream>>>(pre, ln1g + i * CDIM,
                                              ln1b + i * CDIM, x1b, x1bf);
        // H = relu(x1@W1^T + b1)
        gemm_bf16_kernel<128, 128, 64, 64><<<dim3(8, 128), 256, 0, stream>>>(
            x1bf, nullptr, 0, i, W1b, b1i, nullptr, nullptr, Hbf,
            NT, FFDIM, CDIM, 1);
        // x2pre = x1 + H@W2^T + b2 -> pre (fp32)
        gemm_bf16_kernel<64, 128, 64, 32><<<dim3(2, 256), 256, 0, stream>>>(
            Hbf, nullptr, 0, i, W2b, b2i, x1b, pre, nullptr,
            NT, CDIM, FFDIM, 0);
        // act = LN3(pre)
        ln_kernel<<<NT / 4, 256, 0, stream>>>(pre, ln3g + i * CDIM,
                                              ln3b + i * CDIM, act, actbf);
    }

    // final output: act (B,T,C) -> out (B,C,T)
    transpose_kernel<<<dim3(CDIM / 32, TLEN / 32, BQ), dim3(32, 8), 0, stream>>>(
        act, out, nullptr, TLEN, CDIM);
}

// Round 4
// 504.709 us; speedup vs baseline: 5.1148x; 1.3109x over previous
//
#include <hip/hip_runtime.h>
#include <math.h>

// Problem constants
#define BQ      16          // batch
#define CDIM    256         // model dim
#define TLEN    1024        // sequence length
#define CTXL    48          // context length
#define CHUNKL  16
#define NLAYER  4
#define NHEADS  8
#define DHEAD   32          // 256/8
#define FFDIM   1024
#define NWIN    64          // T / CHUNK
#define EXTL    1072        // CTX_LEN + T
#define QKV_N   768

typedef __attribute__((ext_vector_type(4))) float floatx4;
typedef __attribute__((ext_vector_type(8))) __bf16 bf16x8;

__device__ __forceinline__ unsigned short f2bf(float f) {
    unsigned int u = __float_as_uint(f);
    u += 0x7fff + ((u >> 16) & 1);          // RNE
    return (unsigned short)(u >> 16);
}
__device__ __forceinline__ float bf2f(unsigned short h) {
    return __uint_as_float(((unsigned int)h) << 16);
}

// ---------------------------------------------------------------------------
// fp32 -> bf16 bulk convert (n divisible by 4)
// ---------------------------------------------------------------------------
__global__ void f2b_kernel(const float* __restrict__ in,
                           unsigned short* __restrict__ out, int n) {
    int i = (blockIdx.x * 256 + threadIdx.x) * 4;
    if (i < n) {
        float4 v = *(const float4*)(in + i);
        ushort4 o;
        o.x = f2bf(v.x); o.y = f2bf(v.y); o.z = f2bf(v.z); o.w = f2bf(v.w);
        *(ushort4*)(out + i) = o;
    }
}

// ---------------------------------------------------------------------------
// Depthwise causal conv (fp32 in/out)
// ---------------------------------------------------------------------------
__global__ void conv_kernel(const float* __restrict__ x,
                            const float* __restrict__ emb,
                            float* __restrict__ tmp) {
    int bc = blockIdx.x;
    int b = bc >> 8, c = bc & 255;
    __shared__ float xs[31 + TLEN];
    __shared__ float f[32];
    int t = threadIdx.x;
    if (t < 31) xs[t] = 0.f;
    const float* xrow = x + (size_t)bc * TLEN;
    for (int s = t; s < TLEN; s += 256) xs[31 + s] = xrow[s];
    if (t < 32) {
        const float* e0 = emb + (((size_t)b * 2 + 0) * CDIM + c) * 32;
        const float* e1 = emb + (((size_t)b * 2 + 1) * CDIM + c) * 32;
        f[t] = 0.5f * (e0[t] + e1[t]);
    }
    __syncthreads();
    float* orow = tmp + (size_t)bc * TLEN;
    for (int s = t; s < TLEN; s += 256) {
        float acc = 0.f;
#pragma unroll
        for (int l = 0; l < 32; ++l) acc += f[l] * xs[s + l];
        orow[s] = acc;
    }
}

// ---------------------------------------------------------------------------
// Transpose fp32 (B,R,S) -> bf16 (B,S,R)
// ---------------------------------------------------------------------------
__global__ void transpose_f2b_kernel(const float* __restrict__ in,
                                     unsigned short* __restrict__ out,
                                     int R, int S) {
    __shared__ float tile[32][33];
    int b = blockIdx.z;
    int s0 = blockIdx.x * 32, r0 = blockIdx.y * 32;
    const float* inb = in + (size_t)b * R * S;
    unsigned short* outb = out + (size_t)b * R * S;
    int tx = threadIdx.x, ty = threadIdx.y;
    for (int i = ty; i < 32; i += 8)
        tile[i][tx] = inb[(size_t)(r0 + i) * S + s0 + tx];
    __syncthreads();
    for (int i = ty; i < 32; i += 8)
        outb[(size_t)(s0 + i) * R + r0 + tx] = f2bf(tile[tx][i]);
}

// ---------------------------------------------------------------------------
// Transpose bf16 (B,R,S) -> fp32 (B,S,R)   (final output)
// ---------------------------------------------------------------------------
__global__ void transpose_b2f_kernel(const unsigned short* __restrict__ in,
                                     float* __restrict__ out,
                                     int R, int S) {
    __shared__ float tile[32][33];
    int b = blockIdx.z;
    int s0 = blockIdx.x * 32, r0 = blockIdx.y * 32;
    const unsigned short* inb = in + (size_t)b * R * S;
    float* outb = out + (size_t)b * R * S;
    int tx = threadIdx.x, ty = threadIdx.y;
    for (int i = ty; i < 32; i += 8)
        tile[i][tx] = bf2f(inb[(size_t)(r0 + i) * S + s0 + tx]);
    __syncthreads();
    for (int i = ty; i < 32; i += 8)
        outb[(size_t)(s0 + i) * R + r0 + tx] = tile[tx][i];
}

// ---------------------------------------------------------------------------
// ctx_out[b][layer][r][c] = actbf[b][976+r][c]  (bf16 -> fp32)
// ---------------------------------------------------------------------------
__global__ void ctx_copy_kernel(const unsigned short* __restrict__ act,
                                float* __restrict__ ctx_out, int layer) {
    int idx = blockIdx.x * 256 + threadIdx.x;
    int c = idx & 255;
    int r = (idx >> 8) % CTXL;
    int b = idx / (CTXL * CDIM);
    ctx_out[(((size_t)b * NLAYER + layer) * CTXL + r) * CDIM + c] =
        bf2f(act[((size_t)b * TLEN + (TLEN - CTXL) + r) * CDIM + c]);
}

// ---------------------------------------------------------------------------
// bf16 MFMA GEMM (templated tile): out[m][n] = sum_k Arow(m)[k]*W[n][k]
//   + bias[n] (relu optional). BK=64, 256 threads, bf16 output.
// Staging via global_load_lds 16B, XOR-swizzled chunks:
//   chunk (row,kc) at row*8 + (kc ^ (row&7)).
// mode 1 (ext tokens): row -> ctxb (e<48) or A (e-48).
// ---------------------------------------------------------------------------
template<int BM, int BN, int WM, int WN>
__global__ __launch_bounds__(256) void gemm_bf16_kernel(
    const unsigned short* __restrict__ A,
    const unsigned short* __restrict__ ctxb,
    int mode, int layer,
    const unsigned short* __restrict__ W,
    const float* __restrict__ bias,
    unsigned short* __restrict__ outb,
    int M, int N, int K, int relu) {
    constexpr int IA = BM / 32;
    constexpr int IB = BN / 32;
    constexpr int MT = WM / 16;
    constexpr int NTT = WN / 16;
    constexpr int NWX = BN / WN;
    __shared__ __align__(16) char smem[(BM + BN) * 128];
    char* smemA = smem;
    char* smemB = smem + BM * 128;
    int tid = threadIdx.x;
    int lane = tid & 63;
    int wid = tid >> 6;
    int ln = lane & 15, kq = lane >> 4;
    int wm = (wid / NWX) * WM, wn = (wid % NWX) * WN;
    int m0 = blockIdx.y * BM, n0 = blockIdx.x * BN;

    const unsigned short* arow[IA];
    int akc[IA];
    const unsigned short* brow[IB];
    int bkc[IB];
#pragma unroll
    for (int is = 0; is < IA; ++is) {
        int q = tid + is * 256;
        int m = q >> 3;
        akc[is] = ((q & 7) ^ (m & 7)) * 8;
        int mg = m0 + m;
        if (mode == 0) {
            arow[is] = A + (size_t)mg * K;
        } else {
            int b = mg / EXTL;
            int e = mg - b * EXTL;
            arow[is] = (e < CTXL)
                ? ctxb + (((size_t)b * NLAYER + layer) * CTXL + e) * CDIM
                : A + ((size_t)b * TLEN + (e - CTXL)) * CDIM;
        }
    }
#pragma unroll
    for (int is = 0; is < IB; ++is) {
        int q = tid + is * 256;
        int m = q >> 3;
        bkc[is] = ((q & 7) ^ (m & 7)) * 8;
        brow[is] = W + (size_t)(n0 + m) * K;
    }

    floatx4 acc[MT][NTT];
#pragma unroll
    for (int i = 0; i < MT; ++i)
#pragma unroll
        for (int j = 0; j < NTT; ++j) acc[i][j] = (floatx4){0.f, 0.f, 0.f, 0.f};

    for (int kt = 0; kt < K; kt += 64) {
#pragma unroll
        for (int is = 0; is < IA; ++is) {
            int off = (is * 256 + tid) * 16;
            __builtin_amdgcn_global_load_lds(
                (const __attribute__((address_space(1))) unsigned int*)
                    (const void*)(arow[is] + kt + akc[is]),
                (__attribute__((address_space(3))) unsigned int*)
                    (void*)(smemA + off), 16, 0, 0);
        }
#pragma unroll
        for (int is = 0; is < IB; ++is) {
            int off = (is * 256 + tid) * 16;
            __builtin_amdgcn_global_load_lds(
                (const __attribute__((address_space(1))) unsigned int*)
                    (const void*)(brow[is] + kt + bkc[is]),
                (__attribute__((address_space(3))) unsigned int*)
                    (void*)(smemB + off), 16, 0, 0);
        }
        __syncthreads();
#pragma unroll
        for (int s = 0; s < 2; ++s) {
            bf16x8 af[MT], bfv[NTT];
            int kc = s * 4 + kq;
#pragma unroll
            for (int i = 0; i < MT; ++i) {
                int ml = wm + 16 * i + ln;
                af[i] = *(const bf16x8*)(smemA + (ml * 8 + (kc ^ (ml & 7))) * 16);
            }
#pragma unroll
            for (int j = 0; j < NTT; ++j) {
                int nl = wn + 16 * j + ln;
                bfv[j] = *(const bf16x8*)(smemB + (nl * 8 + (kc ^ (nl & 7))) * 16);
            }
#pragma unroll
            for (int i = 0; i < MT; ++i)
#pragma unroll
                for (int j = 0; j < NTT; ++j)
                    acc[i][j] = __builtin_amdgcn_mfma_f32_16x16x32_bf16(
                        af[i], bfv[j], acc[i][j], 0, 0, 0);
        }
        __syncthreads();
    }

#pragma unroll
    for (int i = 0; i < MT; ++i) {
#pragma unroll
        for (int r = 0; r < 4; ++r) {
            int m = m0 + wm + 16 * i + kq * 4 + r;
#pragma unroll
            for (int j = 0; j < NTT; ++j) {
                int n = n0 + wn + 16 * j + ln;
                float v = acc[i][j][r] + bias[n];
                if (relu) v = fmaxf(v, 0.f);
                outb[(size_t)m * N + n] = f2bf(v);
            }
        }
    }
}

// ---------------------------------------------------------------------------
// Fused GEMM + residual + LayerNorm (N = 256 fixed).
// out[m][:] = LN( A[m]@W^T + bias + resid[m] ) * g + beta, bf16 out.
// BM=32, BN=256: block owns full output rows -> LN in epilogue via
// cross-wave LDS reduction. 256 threads, 4 waves; wave w covers cols w*64.
// ---------------------------------------------------------------------------
__global__ __launch_bounds__(256) void gemm_ln_kernel(
    const unsigned short* __restrict__ A,
    const unsigned short* __restrict__ W,
    const float* __restrict__ bias,
    const unsigned short* __restrict__ resid,
    const float* __restrict__ g,
    const float* __restrict__ beta,
    unsigned short* __restrict__ outb,
    int M, int K) {
    __shared__ __align__(16) unsigned short smA[32 * 64];    // 4 KB swizzled
    __shared__ __align__(16) unsigned short smB[256 * 64];   // 32 KB
    __shared__ float rsum[32][4];
    __shared__ float rsqs[32][4];
    int tid = threadIdx.x;
    int lane = tid & 63;
    int wid = tid >> 6;
    int ln = lane & 15, quad = lane >> 4;
    int wn = wid * 64;
    int m0 = blockIdx.x * 32;

    const unsigned short* arow =
        A + (size_t)(m0 + (tid >> 3)) * K + ((tid & 7) ^ ((tid >> 3) & 7)) * 8;
    const unsigned short* brow[8];
#pragma unroll
    for (int is = 0; is < 8; ++is) {
        int q = tid + is * 256;
        int mm = q >> 3;
        brow[is] = W + (size_t)mm * K + ((q & 7) ^ (mm & 7)) * 8;
    }

    floatx4 acc[2][4];
#pragma unroll
    for (int i = 0; i < 2; ++i)
#pragma unroll
        for (int j = 0; j < 4; ++j) acc[i][j] = (floatx4){0.f, 0.f, 0.f, 0.f};

    for (int kt = 0; kt < K; kt += 64) {
        __builtin_amdgcn_global_load_lds(
            (const __attribute__((address_space(1))) unsigned int*)
                (const void*)(arow + kt),
            (__attribute__((address_space(3))) unsigned int*)
                (void*)((char*)smA + tid * 16), 16, 0, 0);
#pragma unroll
        for (int is = 0; is < 8; ++is) {
            __builtin_amdgcn_global_load_lds(
                (const __attribute__((address_space(1))) unsigned int*)
                    (const void*)(brow[is] + kt),
                (__attribute__((address_space(3))) unsigned int*)
                    (void*)((char*)smB + (is * 256 + tid) * 16), 16, 0, 0);
        }
        __syncthreads();
#pragma unroll
        for (int s = 0; s < 2; ++s) {
            int kc = s * 4 + quad;
            bf16x8 af[2], bfv[4];
#pragma unroll
            for (int i = 0; i < 2; ++i) {
                int ml = 16 * i + ln;
                af[i] = *(const bf16x8*)(smA + (ml * 8 + (kc ^ (ml & 7))) * 8);
            }
#pragma unroll
            for (int j = 0; j < 4; ++j) {
                int nl = wn + 16 * j + ln;
                bfv[j] = *(const bf16x8*)(smB + (nl * 8 + (kc ^ (nl & 7))) * 8);
            }
#pragma unroll
            for (int i = 0; i < 2; ++i)
#pragma unroll
                for (int j = 0; j < 4; ++j)
                    acc[i][j] = __builtin_amdgcn_mfma_f32_16x16x32_bf16(
                        af[i], bfv[j], acc[i][j], 0, 0, 0);
        }
        __syncthreads();
    }

    // v = acc + bias + resid (fp32), keep in acc
#pragma unroll
    for (int i = 0; i < 2; ++i)
#pragma unroll
        for (int r = 0; r < 4; ++r) {
            int m = m0 + 16 * i + quad * 4 + r;
#pragma unroll
            for (int j = 0; j < 4; ++j) {
                int n = wn + 16 * j + ln;
                acc[i][j][r] += bias[n] + bf2f(resid[(size_t)m * CDIM + n]);
            }
        }

    // cross-wave row stats
#pragma unroll
    for (int i = 0; i < 2; ++i)
#pragma unroll
        for (int r = 0; r < 4; ++r) {
            float s1 = acc[i][0][r] + acc[i][1][r] + acc[i][2][r] + acc[i][3][r];
            float s2 = acc[i][0][r] * acc[i][0][r] + acc[i][1][r] * acc[i][1][r]
                     + acc[i][2][r] * acc[i][2][r] + acc[i][3][r] * acc[i][3][r];
#pragma unroll
            for (int off = 8; off >= 1; off >>= 1) {
                s1 += __shfl_xor(s1, off, 64);
                s2 += __shfl_xor(s2, off, 64);
            }
            if (ln == 0) {
                int row = 16 * i + quad * 4 + r;
                rsum[row][wid] = s1;
                rsqs[row][wid] = s2;
            }
        }
    __syncthreads();

#pragma unroll
    for (int i = 0; i < 2; ++i)
#pragma unroll
        for (int r = 0; r < 4; ++r) {
            int row = 16 * i + quad * 4 + r;
            float tot = rsum[row][0] + rsum[row][1] + rsum[row][2] + rsum[row][3];
            float tsq = rsqs[row][0] + rsqs[row][1] + rsqs[row][2] + rsqs[row][3];
            float mu = tot * (1.f / 256.f);
            float var = tsq * (1.f / 256.f) - mu * mu;
            float inv = rsqrtf(var + 1e-5f);
            int m = m0 + row;
#pragma unroll
            for (int j = 0; j < 4; ++j) {
                int n = wn + 16 * j + ln;
                float y = (acc[i][j][r] - mu) * inv * g[n] + beta[n];
                outb[(size_t)m * CDIM + n] = f2bf(y);
            }
        }
}

// ---------------------------------------------------------------------------
// MFMA windowed attention. One block (256 thr, 4 waves) per (window, batch);
// each wave handles 2 heads. QKV: (B, EXTL, 768) bf16 [Q|K|V sections].
// ---------------------------------------------------------------------------
__global__ __launch_bounds__(256) void attn_mfma_kernel(
    const unsigned short* __restrict__ QKV,
    unsigned short* __restrict__ O) {
    int n = blockIdx.x, b = blockIdx.y;
    __shared__ __align__(16) unsigned short Vt[256][72];      // V^T [d][key]
    __shared__ __align__(16) unsigned short Pb[4][16][72];    // per-wave P
    int tid = threadIdx.x;
    int lane = tid & 63, wid = tid >> 6;
    int ln = lane & 15, quad = lane >> 4;
    int key0 = n * CHUNKL;
    const unsigned short* base = QKV + (size_t)b * EXTL * QKV_N;

    // stage V^T: V[key][d] -> Vt[d][key]
    {
        int row = tid >> 2;              // key 0..63
        int c0 = (tid & 3) * 64;         // d block
        const unsigned short* vrow =
            base + (size_t)(key0 + row) * QKV_N + 512 + c0;
#pragma unroll
        for (int s = 0; s < 8; ++s) {
            bf16x8 v = *(const bf16x8*)(vrow + 8 * s);
#pragma unroll
            for (int j = 0; j < 8; ++j)
                Vt[c0 + 8 * s + j][row] = ((const unsigned short*)&v)[j];
        }
    }
    __syncthreads();

    const float scale = 0.17677669529663687f;   // 1/sqrt(32)
#pragma unroll
    for (int hh = 0; hh < 2; ++hh) {
        int h = wid * 2 + hh;
        bf16x8 qf = *(const bf16x8*)(base
            + (size_t)(CTXL + key0 + ln) * QKV_N + h * DHEAD + quad * 8);
        floatx4 sc[4];
#pragma unroll
        for (int j = 0; j < 4; ++j) {
            bf16x8 kf = *(const bf16x8*)(base
                + (size_t)(key0 + j * 16 + ln) * QKV_N + 256
                + h * DHEAD + quad * 8);
            sc[j] = __builtin_amdgcn_mfma_f32_16x16x32_bf16(
                qf, kf, (floatx4){0.f, 0.f, 0.f, 0.f}, 0, 0, 0);
        }
        float p[4][4];
#pragma unroll
        for (int r = 0; r < 4; ++r) {
            float mx = -1e30f;
#pragma unroll
            for (int j = 0; j < 4; ++j) mx = fmaxf(mx, sc[j][r]);
            mx = fmaxf(mx, __shfl_xor(mx, 1, 64));
            mx = fmaxf(mx, __shfl_xor(mx, 2, 64));
            mx = fmaxf(mx, __shfl_xor(mx, 4, 64));
            mx = fmaxf(mx, __shfl_xor(mx, 8, 64));
            float sum = 0.f;
#pragma unroll
            for (int j = 0; j < 4; ++j) {
                float e = __expf((sc[j][r] - mx) * scale);
                p[r][j] = e;
                sum += e;
            }
            sum += __shfl_xor(sum, 1, 64);
            sum += __shfl_xor(sum, 2, 64);
            sum += __shfl_xor(sum, 4, 64);
            sum += __shfl_xor(sum, 8, 64);
            float inv = 1.f / sum;
#pragma unroll
            for (int j = 0; j < 4; ++j) p[r][j] *= inv;
        }
#pragma unroll
        for (int r = 0; r < 4; ++r)
#pragma unroll
            for (int j = 0; j < 4; ++j)
                Pb[wid][quad * 4 + r][j * 16 + ln] = f2bf(p[r][j]);
        bf16x8 pa0 = *(const bf16x8*)&Pb[wid][ln][quad * 8];
        bf16x8 pa1 = *(const bf16x8*)&Pb[wid][ln][32 + quad * 8];
        floatx4 o[2];
#pragma unroll
        for (int jt = 0; jt < 2; ++jt) {
            bf16x8 v0 = *(const bf16x8*)&Vt[h * DHEAD + jt * 16 + ln][quad * 8];
            bf16x8 v1 = *(const bf16x8*)&Vt[h * DHEAD + jt * 16 + ln][32 + quad * 8];
            floatx4 a = __builtin_amdgcn_mfma_f32_16x16x32_bf16(
                pa0, v0, (floatx4){0.f, 0.f, 0.f, 0.f}, 0, 0, 0);
            o[jt] = __builtin_amdgcn_mfma_f32_16x16x32_bf16(pa1, v1, a, 0, 0, 0);
        }
        unsigned short* Ob =
            O + ((size_t)b * TLEN + n * CHUNKL) * CDIM + h * DHEAD;
#pragma unroll
        for (int jt = 0; jt < 2; ++jt)
#pragma unroll
            for (int r = 0; r < 4; ++r)
                Ob[(size_t)(quad * 4 + r) * CDIM + jt * 16 + ln] = f2bf(o[jt][r]);
    }
}

// ---------------------------------------------------------------------------
extern "C" void kernel_launch(void* const* d_in, const int* in_sizes, int n_in,
                              void* d_out, int out_size, void* d_ws, size_t ws_size,
                              hipStream_t stream) {
    const float* x    = (const float*)d_in[0];
    const float* emb  = (const float*)d_in[1];
    const float* ctx  = (const float*)d_in[2];
    const float* Wqkv = (const float*)d_in[3];
    const float* bqkv = (const float*)d_in[4];
    const float* Wo   = (const float*)d_in[5];
    const float* bo   = (const float*)d_in[6];
    const float* W1   = (const float*)d_in[7];
    const float* b1   = (const float*)d_in[8];
    const float* W2   = (const float*)d_in[9];
    const float* b2   = (const float*)d_in[10];
    const float* ln1g = (const float*)d_in[11];
    const float* ln1b = (const float*)d_in[12];
    const float* ln3g = (const float*)d_in[13];
    const float* ln3b = (const float*)d_in[14];

    float* out = (float*)d_out;                        // (B, C, T)
    float* ctx_out = out + (size_t)BQ * CDIM * TLEN;   // (B, 4, 48, C)

    // Workspace layout (bytes, total ~110 MB)
    char* w = (char*)d_ws;
    float* convt = (float*)w;         w += 16777216;   // conv tmp (B,C,T) fp32
    unsigned short* actbf  = (unsigned short*)w; w += 8388608;   // (B,T,C)
    unsigned short* x1bf   = (unsigned short*)w; w += 8388608;
    unsigned short* Obf    = (unsigned short*)w; w += 8388608;
    unsigned short* QKVbf  = (unsigned short*)w; w += 26345472;  // (B,1072,768)
    unsigned short* Hbf    = (unsigned short*)w; w += 33554432;  // (B,T,FF)
    unsigned short* ctxbf  = (unsigned short*)w; w += 1572864;
    unsigned short* Wqkvbf = (unsigned short*)w; w += 1572864;
    unsigned short* Wobf   = (unsigned short*)w; w += 524288;
    unsigned short* W1bf   = (unsigned short*)w; w += 2097152;
    unsigned short* W2bf   = (unsigned short*)w; w += 2097152;

    const int NT = BQ * TLEN;   // 16384

    // weight / ctx conversions to bf16
    f2b_kernel<<<768, 256, 0, stream>>>(Wqkv, Wqkvbf, NLAYER * 3 * CDIM * CDIM);
    f2b_kernel<<<256, 256, 0, stream>>>(Wo, Wobf, NLAYER * CDIM * CDIM);
    f2b_kernel<<<1024, 256, 0, stream>>>(W1, W1bf, NLAYER * FFDIM * CDIM);
    f2b_kernel<<<1024, 256, 0, stream>>>(W2, W2bf, NLAYER * CDIM * FFDIM);
    f2b_kernel<<<768, 256, 0, stream>>>(ctx, ctxbf, BQ * NLAYER * CTXL * CDIM);

    // conv -> convt (B,C,T) fp32, transpose -> actbf (B,T,C) bf16
    conv_kernel<<<BQ * CDIM, 256, 0, stream>>>(x, emb, convt);
    transpose_f2b_kernel<<<dim3(TLEN / 32, CDIM / 32, BQ), dim3(32, 8), 0,
                           stream>>>(convt, actbf, CDIM, TLEN);

    for (int i = 0; i < NLAYER; ++i) {
        const unsigned short* Wqkvb = Wqkvbf + (size_t)i * 3 * CDIM * CDIM;
        const float* bqi = bqkv + (size_t)i * 3 * CDIM;
        const unsigned short* Wob = Wobf + (size_t)i * CDIM * CDIM;
        const float* boi = bo + (size_t)i * CDIM;
        const unsigned short* W1b = W1bf + (size_t)i * FFDIM * CDIM;
        const float* b1i = b1 + (size_t)i * FFDIM;
        const unsigned short* W2b = W2bf + (size_t)i * CDIM * FFDIM;
        const float* b2i = b2 + (size_t)i * CDIM;

        ctx_copy_kernel<<<(BQ * CTXL * CDIM) / 256, 256, 0, stream>>>(
            actbf, ctx_out, i);
        // QKV = [ctx|act] @ Wqkv^T + bqkv  (M=17152, N=768, K=256)
        gemm_bf16_kernel<128, 128, 64, 64><<<dim3(6, 134), 256, 0, stream>>>(
            actbf, ctxbf, 1, i, Wqkvb, bqi, QKVbf, BQ * EXTL, QKV_N, CDIM, 0);
        // attention -> Obf
        attn_mfma_kernel<<<dim3(NWIN, BQ), 256, 0, stream>>>(QKVbf, Obf);
        // x1 = LN1(act + O@Wo^T + bo) -> x1bf  (fused)
        gemm_ln_kernel<<<NT / 32, 256, 0, stream>>>(
            Obf, Wob, boi, actbf, ln1g + i * CDIM, ln1b + i * CDIM,
            x1bf, NT, CDIM);
        // H = relu(x1@W1^T + b1)
        gemm_bf16_kernel<128, 128, 64, 64><<<dim3(8, 128), 256, 0, stream>>>(
            x1bf, nullptr, 0, i, W1b, b1i, Hbf, NT, FFDIM, CDIM, 1);
        // act = LN3(x1 + H@W2^T + b2) -> actbf  (fused)
        gemm_ln_kernel<<<NT / 32, 256, 0, stream>>>(
            Hbf, W2b, b2i, x1bf, ln3g + i * CDIM, ln3b + i * CDIM,
            actbf, NT, FFDIM);
    }

    // final output: actbf (B,T,C) -> out (B,C,T) fp32
    transpose_b2f_kernel<<<dim3(CDIM / 32, TLEN / 32, BQ), dim3(32, 8), 0,
                           stream>>>(actbf, out, TLEN, CDIM);
}